// Round 1
// baseline (600.130 us; speedup 1.0000x reference)
//
#include <hip/hip_runtime.h>
#include <hip/hip_bf16.h>
#include <limits.h>

#define NNODES 100000
#define NEDGES 640000
#define WIDTH  128
#define NFEAT  64
#define KA     192          // edge GEMM K (128 diffs + 64 e_feat)
#define KA_PAD 200          // LDS row stride (bf16 elems): 100 words, %32==4 -> conflict-minimal
#define KB     256          // node GEMM K (128 x + 128 maxes)
#define KB_PAD 264          // 132 words, %32==4
#define MT     64           // rows per tile

typedef __attribute__((ext_vector_type(8))) short short8;   // 8 bf16 = one MFMA A/B frag
typedef __attribute__((ext_vector_type(4))) short short4v;
typedef __attribute__((ext_vector_type(4))) float floatx4;  // MFMA C/D frag

// float -> bf16 bits, round-to-nearest-even (finite inputs only)
__device__ __forceinline__ short f2bf(float f) {
    unsigned u = __float_as_uint(f);
    unsigned r = u + 0x7fffu + ((u >> 16) & 1u);
    return (short)(r >> 16);
}
__device__ __forceinline__ float bf2f(short s) {
    return __uint_as_float(((unsigned)(unsigned short)s) << 16);
}
// order-preserving float<->int for atomicMax-based segment max
__device__ __forceinline__ int encf(float f) {
    int i = __float_as_int(f);
    return i >= 0 ? i : (i ^ 0x7fffffff);
}
__device__ __forceinline__ float decf(int i) {
    int j = i >= 0 ? i : (i ^ 0x7fffffff);
    return __int_as_float(j);
}

// ---------------------------------------------------------------------------
// prep: mEnc[N*128] = INT_MIN sentinel; convert W_edge/W_mlp to bf16 [n][k]
// ---------------------------------------------------------------------------
__global__ __launch_bounds__(256) void prep_kernel(
    const float* __restrict__ W_edge, const float* __restrict__ W_mlp,
    int* __restrict__ mEnc, short* __restrict__ We_t, short* __restrict__ Wm_t)
{
    int t = blockIdx.x * 256 + threadIdx.x;
    int4 v; v.x = v.y = v.z = v.w = INT_MIN;
    if (t < (NNODES * WIDTH) / 4) ((int4*)mEnc)[t] = v;
    if (t < KA * WIDTH) {
        int k = t / WIDTH, n = t % WIDTH;
        We_t[n * KA + k] = f2bf(W_edge[t]);
    } else if (t < (KA + KB) * WIDTH) {
        int j = t - KA * WIDTH;
        int k = j / WIDTH, n = j % WIDTH;
        Wm_t[n * KB + k] = f2bf(W_mlp[j]);
    }
}

// ---------------------------------------------------------------------------
// edge: per 64-edge tile: ef = diffs + relu([diffs,e_feat] @ W_edge + b_edge)
//       then atomicMax(encoded) into mEnc[dst]
// ---------------------------------------------------------------------------
__global__ __launch_bounds__(256) void edge_kernel(
    const float* __restrict__ x, const int* __restrict__ e,
    const float* __restrict__ e_feat, const short* __restrict__ We_t,
    const float* __restrict__ b_edge, int* __restrict__ mEnc)
{
    __shared__ short sA[MT * KA_PAD];
    __shared__ float sBias[WIDTH];
    __shared__ int   sDst[MT];

    const int tid = threadIdx.x;
    if (tid < WIDTH) sBias[tid] = b_edge[tid];

    const int e0 = blockIdx.x * MT;
    const int* eSrc = e;
    const int* eDst = e + NEDGES;
    const float4* xf4 = (const float4*)x;
    const float4* ef4 = (const float4*)e_feat;

    // ---- stage A = [bf16(diffs) | bf16(e_feat)] ----
    {
        int mq = tid >> 5, c = tid & 31;            // 8 rows in flight, 32 f4/row
        #pragma unroll
        for (int mm = mq; mm < MT; mm += 8) {
            int eidx = e0 + mm;
            int s = eSrc[eidx], d = eDst[eidx];
            float4 xs = xf4[(size_t)s * 32 + c];
            float4 xd = xf4[(size_t)d * 32 + c];
            short4v df;
            df.x = f2bf(xd.x - xs.x);
            df.y = f2bf(xd.y - xs.y);
            df.z = f2bf(xd.z - xs.z);
            df.w = f2bf(xd.w - xs.w);
            *(short4v*)&sA[mm * KA_PAD + c * 4] = df;
            if (c == 0) sDst[mm] = d;
        }
        int mq2 = tid >> 4, c2 = tid & 15;          // 16 rows in flight, 16 f4/row
        #pragma unroll
        for (int mm = mq2; mm < MT; mm += 16) {
            float4 fv = ef4[(size_t)(e0 + mm) * 16 + c2];
            short4v sv;
            sv.x = f2bf(fv.x); sv.y = f2bf(fv.y);
            sv.z = f2bf(fv.z); sv.w = f2bf(fv.w);
            *(short4v*)&sA[mm * KA_PAD + WIDTH + c2 * 4] = sv;
        }
    }
    __syncthreads();

    // ---- MFMA: 4 waves, wave w does rows 0..63 x cols [w*32, w*32+32) ----
    const int wave = tid >> 6;
    const int lane = tid & 63;
    const int l15  = lane & 15;
    const int kq   = (lane >> 4) << 3;   // quad*8
    const int quad = lane >> 4;

    floatx4 acc[4][2];
    #pragma unroll
    for (int rt = 0; rt < 4; ++rt)
        #pragma unroll
        for (int ct = 0; ct < 2; ++ct)
            acc[rt][ct] = (floatx4){0.f, 0.f, 0.f, 0.f};

    #pragma unroll
    for (int kc = 0; kc < 6; ++kc) {
        int k0 = kc * 32 + kq;
        short8 a[4];
        #pragma unroll
        for (int rt = 0; rt < 4; ++rt)
            a[rt] = *(const short8*)&sA[(rt * 16 + l15) * KA_PAD + k0];
        short8 b[2];
        #pragma unroll
        for (int ct = 0; ct < 2; ++ct)
            b[ct] = *(const short8*)&We_t[(size_t)(wave * 32 + ct * 16 + l15) * KA + k0];
        #pragma unroll
        for (int rt = 0; rt < 4; ++rt)
            #pragma unroll
            for (int ct = 0; ct < 2; ++ct)
                acc[rt][ct] = __builtin_amdgcn_mfma_f32_16x16x32_bf16(a[rt], b[ct], acc[rt][ct], 0, 0, 0);
    }

    // ---- epilogue: bias + relu + residual, encoded atomicMax ----
    #pragma unroll
    for (int rt = 0; rt < 4; ++rt) {
        #pragma unroll
        for (int ct = 0; ct < 2; ++ct) {
            int col = wave * 32 + ct * 16 + l15;
            float bias = sBias[col];
            #pragma unroll
            for (int i = 0; i < 4; ++i) {
                int row = rt * 16 + quad * 4 + i;
                float v = acc[rt][ct][i] + bias;
                v = v > 0.f ? v : 0.f;
                float resid = bf2f(sA[row * KA_PAD + col]);   // col < 128: diffs region
                int encv = encf(resid + v);
                atomicMax(&mEnc[(size_t)sDst[row] * WIDTH + col], encv);
            }
        }
    }
}

// ---------------------------------------------------------------------------
// node: out = x + relu([x, maxes] @ W_mlp + b_mlp); maxes decoded in-place
//       from d_out (each row read+written by exactly one block)
// ---------------------------------------------------------------------------
__global__ __launch_bounds__(256) void node_kernel(
    const float* __restrict__ x, const short* __restrict__ Wm_t,
    const float* __restrict__ b_mlp, float* __restrict__ out)
{
    __shared__ short sA[MT * KB_PAD];
    __shared__ float sBias[WIDTH];

    const int tid = threadIdx.x;
    if (tid < WIDTH) sBias[tid] = b_mlp[tid];

    const int n0 = blockIdx.x * MT;
    const float4* xf4 = (const float4*)x;
    const int4* enc4 = (const int4*)out;

    {
        int mq = tid >> 5, c = tid & 31;
        #pragma unroll
        for (int mm = mq; mm < MT; mm += 8) {
            int node = n0 + mm;
            if (node >= NNODES) node = NNODES - 1;
            float4 xv = xf4[(size_t)node * 32 + c];
            short4v sx;
            sx.x = f2bf(xv.x); sx.y = f2bf(xv.y);
            sx.z = f2bf(xv.z); sx.w = f2bf(xv.w);
            *(short4v*)&sA[mm * KB_PAD + c * 4] = sx;
            int4 ev = enc4[(size_t)node * 32 + c];
            short4v sm;
            sm.x = f2bf(ev.x == INT_MIN ? 0.f : decf(ev.x));
            sm.y = f2bf(ev.y == INT_MIN ? 0.f : decf(ev.y));
            sm.z = f2bf(ev.z == INT_MIN ? 0.f : decf(ev.z));
            sm.w = f2bf(ev.w == INT_MIN ? 0.f : decf(ev.w));
            *(short4v*)&sA[mm * KB_PAD + WIDTH + c * 4] = sm;
        }
    }
    __syncthreads();

    const int wave = tid >> 6;
    const int lane = tid & 63;
    const int l15  = lane & 15;
    const int kq   = (lane >> 4) << 3;
    const int quad = lane >> 4;

    floatx4 acc[4][2];
    #pragma unroll
    for (int rt = 0; rt < 4; ++rt)
        #pragma unroll
        for (int ct = 0; ct < 2; ++ct)
            acc[rt][ct] = (floatx4){0.f, 0.f, 0.f, 0.f};

    #pragma unroll
    for (int kc = 0; kc < 8; ++kc) {
        int k0 = kc * 32 + kq;
        short8 a[4];
        #pragma unroll
        for (int rt = 0; rt < 4; ++rt)
            a[rt] = *(const short8*)&sA[(rt * 16 + l15) * KB_PAD + k0];
        short8 b[2];
        #pragma unroll
        for (int ct = 0; ct < 2; ++ct)
            b[ct] = *(const short8*)&Wm_t[(size_t)(wave * 32 + ct * 16 + l15) * KB + k0];
        #pragma unroll
        for (int rt = 0; rt < 4; ++rt)
            #pragma unroll
            for (int ct = 0; ct < 2; ++ct)
                acc[rt][ct] = __builtin_amdgcn_mfma_f32_16x16x32_bf16(a[rt], b[ct], acc[rt][ct], 0, 0, 0);
    }

    #pragma unroll
    for (int rt = 0; rt < 4; ++rt) {
        #pragma unroll
        for (int ct = 0; ct < 2; ++ct) {
            int col = wave * 32 + ct * 16 + l15;
            float bias = sBias[col];
            #pragma unroll
            for (int i = 0; i < 4; ++i) {
                int row = rt * 16 + quad * 4 + i;
                int node = n0 + row;
                if (node < NNODES) {
                    float v = acc[rt][ct][i] + bias;
                    v = v > 0.f ? v : 0.f;
                    out[(size_t)node * WIDTH + col] = x[(size_t)node * WIDTH + col] + v;
                }
            }
        }
    }
}

extern "C" void kernel_launch(void* const* d_in, const int* in_sizes, int n_in,
                              void* d_out, int out_size, void* d_ws, size_t ws_size,
                              hipStream_t stream) {
    const float* x      = (const float*)d_in[0];
    const int*   e      = (const int*)d_in[1];
    const float* e_feat = (const float*)d_in[2];
    const float* W_edge = (const float*)d_in[3];
    const float* b_edge = (const float*)d_in[4];
    const float* W_mlp  = (const float*)d_in[5];
    const float* b_mlp  = (const float*)d_in[6];
    float* out = (float*)d_out;
    int*   mEnc = (int*)d_out;          // segment-max scratch lives in d_out
    short* We_t = (short*)d_ws;                  // [128][192] bf16
    short* Wm_t = We_t + (size_t)KA * WIDTH;     // [128][256] bf16

    prep_kernel<<<(NNODES * WIDTH / 4 + 255) / 256, 256, 0, stream>>>(W_edge, W_mlp, mEnc, We_t, Wm_t);
    edge_kernel<<<NEDGES / MT, 256, 0, stream>>>(x, e, e_feat, We_t, b_edge, mEnc);
    node_kernel<<<(NNODES + MT - 1) / MT, 256, 0, stream>>>(x, Wm_t, b_mlp, out);
}

// Round 2
// 589.768 us; speedup vs baseline: 1.0176x; 1.0176x over previous
//
#include <hip/hip_runtime.h>
#include <hip/hip_bf16.h>
#include <limits.h>

#define NNODES 100000
#define NEDGES 640000
#define WIDTH  128
#define NFEAT  64
#define KA     192          // edge GEMM K (128 diffs + 64 e_feat)
#define KA_PAD 200          // LDS row stride (bf16): 100 words, %32==4 -> conflict-minimal
#define KB     256          // node GEMM K (128 x + 128 maxes)
#define KB_PAD 264
#define MT     64           // rows per tile
#define ST     132          // reduction tile stride (bf16 elems)
#define NB_SCAN ((NNODES + 255) / 256)   // 391

typedef __attribute__((ext_vector_type(8))) short short8;
typedef __attribute__((ext_vector_type(4))) short short4v;
typedef __attribute__((ext_vector_type(4))) float floatx4;

__device__ __forceinline__ short f2bf(float f) {
    unsigned u = __float_as_uint(f);
    unsigned r = u + 0x7fffu + ((u >> 16) & 1u);
    return (short)(r >> 16);
}
__device__ __forceinline__ float bf2f(short s) {
    return __uint_as_float(((unsigned)(unsigned short)s) << 16);
}
// order-preserving float<->int for max
__device__ __forceinline__ int encf(float f) {
    int i = __float_as_int(f);
    return i >= 0 ? i : (i ^ 0x7fffffff);
}
__device__ __forceinline__ float decf(int i) {
    int j = i >= 0 ? i : (i ^ 0x7fffffff);
    return __int_as_float(j);
}

// ---------------------------------------------------------------------------
// prep: mEnc sentinel; counts=0; weights -> bf16 [n][k]
// ---------------------------------------------------------------------------
__global__ __launch_bounds__(256) void prep_kernel(
    const float* __restrict__ W_edge, const float* __restrict__ W_mlp,
    int* __restrict__ mEnc, short* __restrict__ We_t, short* __restrict__ Wm_t,
    int* __restrict__ counts)
{
    int t = blockIdx.x * 256 + threadIdx.x;
    int4 v; v.x = v.y = v.z = v.w = INT_MIN;
    if (t < (NNODES * WIDTH) / 4) ((int4*)mEnc)[t] = v;
    if (t < NNODES) counts[t] = 0;
    if (t < KA * WIDTH) {
        int k = t / WIDTH, n = t % WIDTH;
        We_t[n * KA + k] = f2bf(W_edge[t]);
    } else if (t < (KA + KB) * WIDTH) {
        int j = t - KA * WIDTH;
        int k = j / WIDTH, n = j % WIDTH;
        Wm_t[n * KB + k] = f2bf(W_mlp[j]);
    }
}

// ---------------------------------------------------------------------------
// counting sort of edges by dst: hist -> scanA -> scanB -> scanC -> scatter
// ---------------------------------------------------------------------------
__global__ __launch_bounds__(256) void hist_kernel(
    const int* __restrict__ e, int* __restrict__ counts)
{
    int i = blockIdx.x * 256 + threadIdx.x;
    if (i < NEDGES) atomicAdd(&counts[e[NEDGES + i]], 1);
}

__global__ __launch_bounds__(256) void scanA_kernel(
    const int* __restrict__ counts, int* __restrict__ cursor, int* __restrict__ blockSum)
{
    __shared__ int s[256];
    int tid = threadIdx.x;
    int n = blockIdx.x * 256 + tid;
    int c = (n < NNODES) ? counts[n] : 0;
    s[tid] = c;
    __syncthreads();
    for (int off = 1; off < 256; off <<= 1) {
        int v = (tid >= off) ? s[tid - off] : 0;
        __syncthreads();
        s[tid] += v;
        __syncthreads();
    }
    if (n < NNODES) cursor[n] = s[tid] - c;     // exclusive within block
    if (tid == 255) blockSum[blockIdx.x] = s[255];
}

__global__ __launch_bounds__(512) void scanB_kernel(int* __restrict__ blockSum,
                                                    int* __restrict__ blockOff)
{
    __shared__ int s[512];
    int tid = threadIdx.x;
    int c = (tid < NB_SCAN) ? blockSum[tid] : 0;
    s[tid] = c;
    __syncthreads();
    for (int off = 1; off < 512; off <<= 1) {
        int v = (tid >= off) ? s[tid - off] : 0;
        __syncthreads();
        s[tid] += v;
        __syncthreads();
    }
    if (tid < NB_SCAN) blockOff[tid] = s[tid] - c;  // exclusive
}

__global__ __launch_bounds__(256) void scanC_kernel(
    int* __restrict__ cursor, const int* __restrict__ blockOff)
{
    int n = blockIdx.x * 256 + threadIdx.x;
    if (n < NNODES) cursor[n] += blockOff[blockIdx.x];
}

__global__ __launch_bounds__(256) void scatter_kernel(
    const int* __restrict__ e, int* __restrict__ cursor, int* __restrict__ perm)
{
    int i = blockIdx.x * 256 + threadIdx.x;
    if (i < NEDGES) {
        int d = e[NEDGES + i];
        int p = atomicAdd(&cursor[d], 1);
        perm[p] = i;
    }
}

// ---------------------------------------------------------------------------
// edge (dst-sorted): ef = diffs + relu([diffs,e_feat] @ W_edge + b); in-LDS
// segmented max over dst-runs; plain store for tile-exclusive runs, atomicMax
// only for runs crossing tile boundaries.
// ---------------------------------------------------------------------------
__global__ __launch_bounds__(256) void edge_kernel(
    const float* __restrict__ x, const int* __restrict__ e,
    const float* __restrict__ e_feat, const short* __restrict__ We_t,
    const float* __restrict__ b_edge, const int* __restrict__ perm,
    int* __restrict__ mEnc)
{
    __shared__ short sA[MT * KA_PAD];   // staging; reused as bf16 result tile (stride ST)
    __shared__ float sBias[WIDTH];
    __shared__ int   sDst[MT];
    __shared__ int   sHeadRow[MT + 1];
    __shared__ int   sMeta[3];          // nheads, prevSame, nextSame

    const int tid = threadIdx.x;
    if (tid < WIDTH) sBias[tid] = b_edge[tid];

    const int e0 = blockIdx.x * MT;
    const int* eSrc = e;
    const int* eDst = e + NEDGES;
    const float4* xf4 = (const float4*)x;
    const float4* ef4 = (const float4*)e_feat;

    // ---- stage A = [bf16(diffs) | bf16(e_feat)] in sorted order ----
    {
        int mq = tid >> 5, c = tid & 31;
        #pragma unroll
        for (int mm = mq; mm < MT; mm += 8) {
            int eid = perm[e0 + mm];
            int s = eSrc[eid], d = eDst[eid];
            float4 xs = xf4[(size_t)s * 32 + c];
            float4 xd = xf4[(size_t)d * 32 + c];
            short4v df;
            df.x = f2bf(xd.x - xs.x);
            df.y = f2bf(xd.y - xs.y);
            df.z = f2bf(xd.z - xs.z);
            df.w = f2bf(xd.w - xs.w);
            *(short4v*)&sA[mm * KA_PAD + c * 4] = df;
            if (c == 0) sDst[mm] = d;
        }
        int mq2 = tid >> 4, c2 = tid & 15;
        #pragma unroll
        for (int mm = mq2; mm < MT; mm += 16) {
            int eid = perm[e0 + mm];
            float4 fv = ef4[(size_t)eid * 16 + c2];
            short4v sv;
            sv.x = f2bf(fv.x); sv.y = f2bf(fv.y);
            sv.z = f2bf(fv.z); sv.w = f2bf(fv.w);
            *(short4v*)&sA[mm * KA_PAD + WIDTH + c2 * 4] = sv;
        }
    }
    __syncthreads();

    // ---- run-head detection (wave 0) ----
    if (tid < 64) {
        bool head = (tid == 0) || (sDst[tid] != sDst[tid - 1]);
        unsigned long long mask = __ballot(head);
        int rank = __popcll(mask & ((1ull << tid) - 1ull));
        if (head) sHeadRow[rank] = tid;
        if (tid == 0) {
            int nh = (int)__popcll(mask);
            sMeta[0] = nh;
            sHeadRow[nh] = MT;
            int prevSame = 0, nextSame = 0;
            if (e0 > 0)            prevSame = (eDst[perm[e0 - 1]]  == sDst[0]);
            if (e0 + MT < NEDGES)  nextSame = (eDst[perm[e0 + MT]] == sDst[MT - 1]);
            sMeta[1] = prevSame; sMeta[2] = nextSame;
        }
    }

    // ---- MFMA: 4 waves, wave w -> rows 0..63 x cols [w*32, w*32+32) ----
    const int wave = tid >> 6;
    const int lane = tid & 63;
    const int l15  = lane & 15;
    const int kq   = (lane >> 4) << 3;
    const int quad = lane >> 4;

    floatx4 acc[4][2];
    #pragma unroll
    for (int rt = 0; rt < 4; ++rt)
        #pragma unroll
        for (int ct = 0; ct < 2; ++ct)
            acc[rt][ct] = (floatx4){0.f, 0.f, 0.f, 0.f};

    #pragma unroll
    for (int kc = 0; kc < 6; ++kc) {
        int k0 = kc * 32 + kq;
        short8 a[4];
        #pragma unroll
        for (int rt = 0; rt < 4; ++rt)
            a[rt] = *(const short8*)&sA[(rt * 16 + l15) * KA_PAD + k0];
        short8 b[2];
        #pragma unroll
        for (int ct = 0; ct < 2; ++ct)
            b[ct] = *(const short8*)&We_t[(size_t)(wave * 32 + ct * 16 + l15) * KA + k0];
        #pragma unroll
        for (int rt = 0; rt < 4; ++rt)
            #pragma unroll
            for (int ct = 0; ct < 2; ++ct)
                acc[rt][ct] = __builtin_amdgcn_mfma_f32_16x16x32_bf16(a[rt], b[ct], acc[rt][ct], 0, 0, 0);
    }

    // ---- ef = resid + relu(acc + bias), in registers ----
    #pragma unroll
    for (int rt = 0; rt < 4; ++rt) {
        #pragma unroll
        for (int ct = 0; ct < 2; ++ct) {
            int col = wave * 32 + ct * 16 + l15;
            float bias = sBias[col];
            #pragma unroll
            for (int i = 0; i < 4; ++i) {
                int row = rt * 16 + quad * 4 + i;
                float v = acc[rt][ct][i] + bias;
                v = v > 0.f ? v : 0.f;
                acc[rt][ct][i] = v + bf2f(sA[row * KA_PAD + col]);
            }
        }
    }
    __syncthreads();   // everyone done reading sA; sHeadRow/sMeta published

    // ---- write bf16 result tile (reusing sA) ----
    short* sT = sA;
    #pragma unroll
    for (int rt = 0; rt < 4; ++rt) {
        #pragma unroll
        for (int ct = 0; ct < 2; ++ct) {
            int col = wave * 32 + ct * 16 + l15;
            #pragma unroll
            for (int i = 0; i < 4; ++i) {
                int row = rt * 16 + quad * 4 + i;
                sT[row * ST + col] = f2bf(acc[rt][ct][i]);
            }
        }
    }
    __syncthreads();

    // ---- segmented max over runs; store or boundary-atomic ----
    const int nh = sMeta[0], prevSame = sMeta[1], nextSame = sMeta[2];
    for (int p = tid; p < nh * WIDTH; p += 256) {
        int h = p >> 7, col = p & 127;
        int r0 = sHeadRow[h], r1 = sHeadRow[h + 1];
        float m = bf2f(sT[r0 * ST + col]);
        for (int r = r0 + 1; r < r1; ++r)
            m = fmaxf(m, bf2f(sT[r * ST + col]));
        int dst = sDst[r0];
        int ev = encf(m);
        bool atom = (h == 0 && prevSame) || (h == nh - 1 && nextSame);
        if (atom) atomicMax(&mEnc[(size_t)dst * WIDTH + col], ev);
        else      mEnc[(size_t)dst * WIDTH + col] = ev;
    }
}

// ---------------------------------------------------------------------------
// node: out = x + relu([x, maxes] @ W_mlp + b_mlp)
// ---------------------------------------------------------------------------
__global__ __launch_bounds__(256) void node_kernel(
    const float* __restrict__ x, const short* __restrict__ Wm_t,
    const float* __restrict__ b_mlp, float* __restrict__ out)
{
    __shared__ short sA[MT * KB_PAD];
    __shared__ float sBias[WIDTH];

    const int tid = threadIdx.x;
    if (tid < WIDTH) sBias[tid] = b_mlp[tid];

    const int n0 = blockIdx.x * MT;
    const float4* xf4 = (const float4*)x;
    const int4* enc4 = (const int4*)out;

    {
        int mq = tid >> 5, c = tid & 31;
        #pragma unroll
        for (int mm = mq; mm < MT; mm += 8) {
            int node = n0 + mm;
            if (node >= NNODES) node = NNODES - 1;
            float4 xv = xf4[(size_t)node * 32 + c];
            short4v sx;
            sx.x = f2bf(xv.x); sx.y = f2bf(xv.y);
            sx.z = f2bf(xv.z); sx.w = f2bf(xv.w);
            *(short4v*)&sA[mm * KB_PAD + c * 4] = sx;
            int4 ev = enc4[(size_t)node * 32 + c];
            short4v sm;
            sm.x = f2bf(ev.x == INT_MIN ? 0.f : decf(ev.x));
            sm.y = f2bf(ev.y == INT_MIN ? 0.f : decf(ev.y));
            sm.z = f2bf(ev.z == INT_MIN ? 0.f : decf(ev.z));
            sm.w = f2bf(ev.w == INT_MIN ? 0.f : decf(ev.w));
            *(short4v*)&sA[mm * KB_PAD + WIDTH + c * 4] = sm;
        }
    }
    __syncthreads();

    const int wave = tid >> 6;
    const int lane = tid & 63;
    const int l15  = lane & 15;
    const int kq   = (lane >> 4) << 3;
    const int quad = lane >> 4;

    floatx4 acc[4][2];
    #pragma unroll
    for (int rt = 0; rt < 4; ++rt)
        #pragma unroll
        for (int ct = 0; ct < 2; ++ct)
            acc[rt][ct] = (floatx4){0.f, 0.f, 0.f, 0.f};

    #pragma unroll
    for (int kc = 0; kc < 8; ++kc) {
        int k0 = kc * 32 + kq;
        short8 a[4];
        #pragma unroll
        for (int rt = 0; rt < 4; ++rt)
            a[rt] = *(const short8*)&sA[(rt * 16 + l15) * KB_PAD + k0];
        short8 b[2];
        #pragma unroll
        for (int ct = 0; ct < 2; ++ct)
            b[ct] = *(const short8*)&Wm_t[(size_t)(wave * 32 + ct * 16 + l15) * KB + k0];
        #pragma unroll
        for (int rt = 0; rt < 4; ++rt)
            #pragma unroll
            for (int ct = 0; ct < 2; ++ct)
                acc[rt][ct] = __builtin_amdgcn_mfma_f32_16x16x32_bf16(a[rt], b[ct], acc[rt][ct], 0, 0, 0);
    }

    #pragma unroll
    for (int rt = 0; rt < 4; ++rt) {
        #pragma unroll
        for (int ct = 0; ct < 2; ++ct) {
            int col = wave * 32 + ct * 16 + l15;
            float bias = sBias[col];
            #pragma unroll
            for (int i = 0; i < 4; ++i) {
                int row = rt * 16 + quad * 4 + i;
                int node = n0 + row;
                if (node < NNODES) {
                    float v = acc[rt][ct][i] + bias;
                    v = v > 0.f ? v : 0.f;
                    out[(size_t)node * WIDTH + col] = x[(size_t)node * WIDTH + col] + v;
                }
            }
        }
    }
}

extern "C" void kernel_launch(void* const* d_in, const int* in_sizes, int n_in,
                              void* d_out, int out_size, void* d_ws, size_t ws_size,
                              hipStream_t stream) {
    const float* x      = (const float*)d_in[0];
    const int*   e      = (const int*)d_in[1];
    const float* e_feat = (const float*)d_in[2];
    const float* W_edge = (const float*)d_in[3];
    const float* b_edge = (const float*)d_in[4];
    const float* W_mlp  = (const float*)d_in[5];
    const float* b_mlp  = (const float*)d_in[6];
    float* out  = (float*)d_out;
    int*   mEnc = (int*)d_out;                   // segment-max lives in d_out

    short* We_t = (short*)d_ws;                           // [128][192] bf16
    short* Wm_t = We_t + (size_t)KA * WIDTH;              // [128][256] bf16
    int* counts   = (int*)((char*)d_ws + 114688);         // [N]
    int* cursor   = counts + NNODES;                      // [N]
    int* blockSum = cursor + NNODES;                      // [NB_SCAN]
    int* blockOff = blockSum + NB_SCAN;                   // [NB_SCAN]
    int* perm     = blockOff + NB_SCAN;                   // [E]

    prep_kernel<<<(NNODES * WIDTH / 4 + 255) / 256, 256, 0, stream>>>(
        W_edge, W_mlp, mEnc, We_t, Wm_t, counts);
    hist_kernel<<<(NEDGES + 255) / 256, 256, 0, stream>>>(e, counts);
    scanA_kernel<<<NB_SCAN, 256, 0, stream>>>(counts, cursor, blockSum);
    scanB_kernel<<<1, 512, 0, stream>>>(blockSum, blockOff);
    scanC_kernel<<<NB_SCAN, 256, 0, stream>>>(cursor, blockOff);
    scatter_kernel<<<(NEDGES + 255) / 256, 256, 0, stream>>>(e, cursor, perm);
    edge_kernel<<<NEDGES / MT, 256, 0, stream>>>(x, e, e_feat, We_t, b_edge, perm, mEnc);
    node_kernel<<<(NNODES + MT - 1) / MT, 256, 0, stream>>>(x, Wm_t, b_mlp, out);
}

// Round 3
// 498.176 us; speedup vs baseline: 1.2047x; 1.1839x over previous
//
#include <hip/hip_runtime.h>
#include <hip/hip_bf16.h>
#include <limits.h>

#define NNODES 100000
#define NEDGES 640000
#define WIDTH  128
#define NFEAT  64
#define KA     192          // edge GEMM K (128 diffs + 64 e_feat)
#define KA_PAD 200          // LDS row stride (bf16): 100 words, %32==4
#define KB     256          // node GEMM K (128 x + 128 maxes)
#define KB_PAD 264
#define MT     64           // rows per tile
#define ST     130          // result tile stride in shorts (65 words, odd -> conflict-free)
#define NB_SCAN ((NNODES + 255) / 256)   // 391

typedef __attribute__((ext_vector_type(8))) short short8;
typedef __attribute__((ext_vector_type(4))) short short4v;
typedef __attribute__((ext_vector_type(4))) float floatx4;

// round-to-nearest-even float->bf16 (used once, for weights)
__device__ __forceinline__ short f2bf_rne(float f) {
    unsigned u = __float_as_uint(f);
    unsigned r = u + 0x7fffu + ((u >> 16) & 1u);
    return (short)(r >> 16);
}
// truncating float->bf16 (cheap, staging only; <=1ulp err)
__device__ __forceinline__ short f2bf_t(float f) {
    return (short)(__float_as_uint(f) >> 16);
}
__device__ __forceinline__ float bf2f(short s) {
    return __uint_as_float(((unsigned)(unsigned short)s) << 16);
}
// order-preserving float<->unsigned; encu(x) > 0 for all non-(-NaN) floats,
// so 0x00000000 (memset) is the "empty segment" sentinel
__device__ __forceinline__ unsigned encu(float f) {
    unsigned u = __float_as_uint(f);
    return (u & 0x80000000u) ? ~u : (u | 0x80000000u);
}
__device__ __forceinline__ float decu(unsigned e) {
    unsigned u = (e & 0x80000000u) ? (e ^ 0x80000000u) : ~e;
    return __uint_as_float(u);
}

// ---------------------------------------------------------------------------
// prep: weights -> bf16 [n][k] (RNE)
// ---------------------------------------------------------------------------
__global__ __launch_bounds__(256) void prep_kernel(
    const float* __restrict__ W_edge, const float* __restrict__ W_mlp,
    short* __restrict__ We_t, short* __restrict__ Wm_t)
{
    int t = blockIdx.x * 256 + threadIdx.x;
    if (t < KA * WIDTH) {
        int k = t / WIDTH, n = t % WIDTH;
        We_t[n * KA + k] = f2bf_rne(W_edge[t]);
    } else if (t < (KA + KB) * WIDTH) {
        int j = t - KA * WIDTH;
        int k = j / WIDTH, n = j % WIDTH;
        Wm_t[n * KB + k] = f2bf_rne(W_mlp[j]);
    }
}

// ---------------------------------------------------------------------------
// counting sort by dst: hist -> scanA -> scanB -> scatter (emits src/dst/eid
// in sorted order so edge_kernel has no indirection chain)
// ---------------------------------------------------------------------------
__global__ __launch_bounds__(256) void hist_kernel(
    const int* __restrict__ e, int* __restrict__ counts)
{
    int i = blockIdx.x * 256 + threadIdx.x;
    if (i < NEDGES) atomicAdd(&counts[e[NEDGES + i]], 1);
}

__global__ __launch_bounds__(256) void scanA_kernel(
    const int* __restrict__ counts, int* __restrict__ cursor, int* __restrict__ blockSum)
{
    __shared__ int s[256];
    int tid = threadIdx.x;
    int n = blockIdx.x * 256 + tid;
    int c = (n < NNODES) ? counts[n] : 0;
    s[tid] = c;
    __syncthreads();
    for (int off = 1; off < 256; off <<= 1) {
        int v = (tid >= off) ? s[tid - off] : 0;
        __syncthreads();
        s[tid] += v;
        __syncthreads();
    }
    if (n < NNODES) cursor[n] = s[tid] - c;     // exclusive within block
    if (tid == 255) blockSum[blockIdx.x] = s[255];
}

__global__ __launch_bounds__(512) void scanB_kernel(int* __restrict__ blockSum,
                                                    int* __restrict__ blockOff)
{
    __shared__ int s[512];
    int tid = threadIdx.x;
    int c = (tid < NB_SCAN) ? blockSum[tid] : 0;
    s[tid] = c;
    __syncthreads();
    for (int off = 1; off < 512; off <<= 1) {
        int v = (tid >= off) ? s[tid - off] : 0;
        __syncthreads();
        s[tid] += v;
        __syncthreads();
    }
    if (tid < NB_SCAN) blockOff[tid] = s[tid] - c;  // exclusive
}

__global__ __launch_bounds__(256) void scatter_kernel(
    const int* __restrict__ e, int* __restrict__ cursor,
    const int* __restrict__ blockOff,
    uint2* __restrict__ pSD, int* __restrict__ pEid)
{
    int i = blockIdx.x * 256 + threadIdx.x;
    if (i < NEDGES) {
        int s = e[i];
        int d = e[NEDGES + i];
        int p = atomicAdd(&cursor[d], 1) + blockOff[d >> 8];
        pSD[p] = make_uint2((unsigned)s, (unsigned)d);
        pEid[p] = i;
    }
}

// ---------------------------------------------------------------------------
// edge (dst-sorted): ef = diffs + relu([diffs,e_feat] @ W_edge + b); in-LDS
// segmented max over dst-runs; plain store for tile-exclusive runs, atomicMax
// only at tile boundaries.
// ---------------------------------------------------------------------------
__global__ __launch_bounds__(256, 4) void edge_kernel(
    const float* __restrict__ x, const float* __restrict__ e_feat,
    const short* __restrict__ We_t, const float* __restrict__ b_edge,
    const uint2* __restrict__ pSD, const int* __restrict__ pEid,
    unsigned* __restrict__ mEnc)
{
    __shared__ short sA[MT * KA_PAD];   // staging; reused as bf16 result tile (stride ST)
    __shared__ float sBias[WIDTH];
    __shared__ int   sDst[MT];
    __shared__ int   sHeadRow[MT + 1];
    __shared__ int   sMeta[3];          // nheads, prevSame, nextSame

    const int tid = threadIdx.x;
    if (tid < WIDTH) sBias[tid] = b_edge[tid];

    const int e0 = blockIdx.x * MT;
    const float4* xf4 = (const float4*)x;
    const float4* ef4 = (const float4*)e_feat;

    // ---- stage A = [bf16(diffs) | bf16(e_feat)], 1-deep gather chains ----
    {
        int mq = tid >> 5, c = tid & 31;
        uint2 sd[8];
        #pragma unroll
        for (int j = 0; j < 8; ++j) sd[j] = pSD[e0 + mq + 8 * j];
        #pragma unroll
        for (int j = 0; j < 8; ++j) {
            int mm = mq + 8 * j;
            float4 xs = xf4[(size_t)sd[j].x * 32 + c];
            float4 xd = xf4[(size_t)sd[j].y * 32 + c];
            short4v df;
            df.x = f2bf_t(xd.x - xs.x);
            df.y = f2bf_t(xd.y - xs.y);
            df.z = f2bf_t(xd.z - xs.z);
            df.w = f2bf_t(xd.w - xs.w);
            *(short4v*)&sA[mm * KA_PAD + c * 4] = df;
            if (c == 0) sDst[mm] = (int)sd[j].y;
        }
        int mq2 = tid >> 4, c2 = tid & 15;
        int eid[4];
        #pragma unroll
        for (int j = 0; j < 4; ++j) eid[j] = pEid[e0 + mq2 + 16 * j];
        #pragma unroll
        for (int j = 0; j < 4; ++j) {
            int mm = mq2 + 16 * j;
            float4 fv = ef4[(size_t)eid[j] * 16 + c2];
            short4v sv;
            sv.x = f2bf_t(fv.x); sv.y = f2bf_t(fv.y);
            sv.z = f2bf_t(fv.z); sv.w = f2bf_t(fv.w);
            *(short4v*)&sA[mm * KA_PAD + WIDTH + c2 * 4] = sv;
        }
    }
    __syncthreads();

    // ---- run-head detection (wave 0) ----
    if (tid < 64) {
        bool head = (tid == 0) || (sDst[tid] != sDst[tid - 1]);
        unsigned long long mask = __ballot(head);
        int rank = __popcll(mask & ((1ull << tid) - 1ull));
        if (head) sHeadRow[rank] = tid;
        if (tid == 0) {
            int nh = (int)__popcll(mask);
            sMeta[0] = nh;
            sHeadRow[nh] = MT;
            int prevSame = 0, nextSame = 0;
            if (e0 > 0)           prevSame = (pSD[e0 - 1].y  == (unsigned)sDst[0]);
            if (e0 + MT < NEDGES) nextSame = (pSD[e0 + MT].y == (unsigned)sDst[MT - 1]);
            sMeta[1] = prevSame; sMeta[2] = nextSame;
        }
    }

    // ---- MFMA: 4 waves, wave w -> rows 0..63 x cols [w*32, w*32+32) ----
    const int wave = tid >> 6;
    const int lane = tid & 63;
    const int l15  = lane & 15;
    const int kq   = (lane >> 4) << 3;
    const int quad = lane >> 4;

    floatx4 acc[4][2];
    #pragma unroll
    for (int rt = 0; rt < 4; ++rt)
        #pragma unroll
        for (int ct = 0; ct < 2; ++ct)
            acc[rt][ct] = (floatx4){0.f, 0.f, 0.f, 0.f};

    #pragma unroll
    for (int kc = 0; kc < 6; ++kc) {
        int k0 = kc * 32 + kq;
        short8 a[4];
        #pragma unroll
        for (int rt = 0; rt < 4; ++rt)
            a[rt] = *(const short8*)&sA[(rt * 16 + l15) * KA_PAD + k0];
        short8 b[2];
        #pragma unroll
        for (int ct = 0; ct < 2; ++ct)
            b[ct] = *(const short8*)&We_t[(size_t)(wave * 32 + ct * 16 + l15) * KA + k0];
        #pragma unroll
        for (int rt = 0; rt < 4; ++rt)
            #pragma unroll
            for (int ct = 0; ct < 2; ++ct)
                acc[rt][ct] = __builtin_amdgcn_mfma_f32_16x16x32_bf16(a[rt], b[ct], acc[rt][ct], 0, 0, 0);
    }

    // ---- ef = resid + relu(acc + bias) ----
    #pragma unroll
    for (int rt = 0; rt < 4; ++rt) {
        #pragma unroll
        for (int ct = 0; ct < 2; ++ct) {
            int col = wave * 32 + ct * 16 + l15;
            float bias = sBias[col];
            #pragma unroll
            for (int i = 0; i < 4; ++i) {
                int row = rt * 16 + quad * 4 + i;
                float v = acc[rt][ct][i] + bias;
                v = v > 0.f ? v : 0.f;
                acc[rt][ct][i] = v + bf2f(sA[row * KA_PAD + col]);
            }
        }
    }
    __syncthreads();   // sA reads done; sHeadRow/sMeta published

    // ---- write bf16 result tile (reusing sA, odd-word stride) ----
    short* sT = sA;
    #pragma unroll
    for (int rt = 0; rt < 4; ++rt) {
        #pragma unroll
        for (int ct = 0; ct < 2; ++ct) {
            int col = wave * 32 + ct * 16 + l15;
            #pragma unroll
            for (int i = 0; i < 4; ++i) {
                int row = rt * 16 + quad * 4 + i;
                sT[row * ST + col] = f2bf_t(acc[rt][ct][i]);
            }
        }
    }
    __syncthreads();

    // ---- segmented max over runs (2 cols per item via b32 reads) ----
    const int nh = sMeta[0], prevSame = sMeta[1], nextSame = sMeta[2];
    const unsigned* sT32 = (const unsigned*)sT;
    for (int p = tid; p < nh * 64; p += 256) {
        int h = p >> 6, cp = p & 63;
        int r0 = sHeadRow[h], r1 = sHeadRow[h + 1];
        unsigned w = sT32[r0 * (ST / 2) + cp];
        float m0 = bf2f((short)(w & 0xffffu));
        float m1 = bf2f((short)(w >> 16));
        for (int r = r0 + 1; r < r1; ++r) {
            unsigned w2 = sT32[r * (ST / 2) + cp];
            m0 = fmaxf(m0, bf2f((short)(w2 & 0xffffu)));
            m1 = fmaxf(m1, bf2f((short)(w2 >> 16)));
        }
        int dst = sDst[r0];
        unsigned ev0 = encu(m0), ev1 = encu(m1);
        unsigned* dp = &mEnc[(size_t)dst * WIDTH + 2 * cp];
        bool atom = (h == 0 && prevSame) || (h == nh - 1 && nextSame);
        if (atom) { atomicMax(dp, ev0); atomicMax(dp + 1, ev1); }
        else      { *(uint2*)dp = make_uint2(ev0, ev1); }
    }
}

// ---------------------------------------------------------------------------
// node: out = x + relu([x, maxes] @ W_mlp + b_mlp)
// ---------------------------------------------------------------------------
__global__ __launch_bounds__(256) void node_kernel(
    const float* __restrict__ x, const short* __restrict__ Wm_t,
    const float* __restrict__ b_mlp, float* __restrict__ out)
{
    __shared__ short sA[MT * KB_PAD];
    __shared__ float sBias[WIDTH];

    const int tid = threadIdx.x;
    if (tid < WIDTH) sBias[tid] = b_mlp[tid];

    const int n0 = blockIdx.x * MT;
    const float4* xf4 = (const float4*)x;
    const uint4* enc4 = (const uint4*)out;

    {
        int mq = tid >> 5, c = tid & 31;
        #pragma unroll
        for (int mm = mq; mm < MT; mm += 8) {
            int node = n0 + mm;
            if (node >= NNODES) node = NNODES - 1;
            float4 xv = xf4[(size_t)node * 32 + c];
            short4v sx;
            sx.x = f2bf_rne(xv.x); sx.y = f2bf_rne(xv.y);
            sx.z = f2bf_rne(xv.z); sx.w = f2bf_rne(xv.w);
            *(short4v*)&sA[mm * KB_PAD + c * 4] = sx;
            uint4 ev = enc4[(size_t)node * 32 + c];
            short4v sm;
            sm.x = f2bf_rne(ev.x == 0u ? 0.f : decu(ev.x));
            sm.y = f2bf_rne(ev.y == 0u ? 0.f : decu(ev.y));
            sm.z = f2bf_rne(ev.z == 0u ? 0.f : decu(ev.z));
            sm.w = f2bf_rne(ev.w == 0u ? 0.f : decu(ev.w));
            *(short4v*)&sA[mm * KB_PAD + WIDTH + c * 4] = sm;
        }
    }
    __syncthreads();

    const int wave = tid >> 6;
    const int lane = tid & 63;
    const int l15  = lane & 15;
    const int kq   = (lane >> 4) << 3;
    const int quad = lane >> 4;

    floatx4 acc[4][2];
    #pragma unroll
    for (int rt = 0; rt < 4; ++rt)
        #pragma unroll
        for (int ct = 0; ct < 2; ++ct)
            acc[rt][ct] = (floatx4){0.f, 0.f, 0.f, 0.f};

    #pragma unroll
    for (int kc = 0; kc < 8; ++kc) {
        int k0 = kc * 32 + kq;
        short8 a[4];
        #pragma unroll
        for (int rt = 0; rt < 4; ++rt)
            a[rt] = *(const short8*)&sA[(rt * 16 + l15) * KB_PAD + k0];
        short8 b[2];
        #pragma unroll
        for (int ct = 0; ct < 2; ++ct)
            b[ct] = *(const short8*)&Wm_t[(size_t)(wave * 32 + ct * 16 + l15) * KB + k0];
        #pragma unroll
        for (int rt = 0; rt < 4; ++rt)
            #pragma unroll
            for (int ct = 0; ct < 2; ++ct)
                acc[rt][ct] = __builtin_amdgcn_mfma_f32_16x16x32_bf16(a[rt], b[ct], acc[rt][ct], 0, 0, 0);
    }

    #pragma unroll
    for (int rt = 0; rt < 4; ++rt) {
        #pragma unroll
        for (int ct = 0; ct < 2; ++ct) {
            int col = wave * 32 + ct * 16 + l15;
            float bias = sBias[col];
            #pragma unroll
            for (int i = 0; i < 4; ++i) {
                int row = rt * 16 + quad * 4 + i;
                int node = n0 + row;
                if (node < NNODES) {
                    float v = acc[rt][ct][i] + bias;
                    v = v > 0.f ? v : 0.f;
                    out[(size_t)node * WIDTH + col] = x[(size_t)node * WIDTH + col] + v;
                }
            }
        }
    }
}

extern "C" void kernel_launch(void* const* d_in, const int* in_sizes, int n_in,
                              void* d_out, int out_size, void* d_ws, size_t ws_size,
                              hipStream_t stream) {
    const float* x      = (const float*)d_in[0];
    const int*   e      = (const int*)d_in[1];
    const float* e_feat = (const float*)d_in[2];
    const float* W_edge = (const float*)d_in[3];
    const float* b_edge = (const float*)d_in[4];
    const float* W_mlp  = (const float*)d_in[5];
    const float* b_mlp  = (const float*)d_in[6];
    float*    out  = (float*)d_out;
    unsigned* mEnc = (unsigned*)d_out;           // segment-max lives in d_out

    short* We_t = (short*)d_ws;                           // [128][192] bf16
    short* Wm_t = We_t + (size_t)KA * WIDTH;              // [128][256] bf16
    int* base     = (int*)((char*)d_ws + 114688);         // 8B-aligned
    uint2* pSD    = (uint2*)base;                         // [E] (src,dst) sorted
    int* pEid     = (int*)(base + 2 * NEDGES);            // [E]
    int* counts   = pEid + NEDGES;                        // [N]
    int* cursor   = counts + NNODES;                      // [N]
    int* blockSum = cursor + NNODES;                      // [NB_SCAN]
    int* blockOff = blockSum + NB_SCAN;                   // [NB_SCAN]

    hipMemsetAsync(d_out, 0, (size_t)NNODES * WIDTH * 4, stream);   // empty = enc 0
    hipMemsetAsync(counts, 0, (size_t)NNODES * 4, stream);
    prep_kernel<<<((KA + KB) * WIDTH + 255) / 256, 256, 0, stream>>>(W_edge, W_mlp, We_t, Wm_t);
    hist_kernel<<<(NEDGES + 255) / 256, 256, 0, stream>>>(e, counts);
    scanA_kernel<<<NB_SCAN, 256, 0, stream>>>(counts, cursor, blockSum);
    scanB_kernel<<<1, 512, 0, stream>>>(blockSum, blockOff);
    scatter_kernel<<<(NEDGES + 255) / 256, 256, 0, stream>>>(e, cursor, blockOff, pSD, pEid);
    edge_kernel<<<NEDGES / MT, 256, 0, stream>>>(x, e_feat, We_t, b_edge, pSD, pEid, mEnc);
    node_kernel<<<(NNODES + MT - 1) / MT, 256, 0, stream>>>(x, Wm_t, b_mlp, out);
}